// Round 8
// baseline (442.493 us; speedup 1.0000x reference)
//
#include <hip/hip_runtime.h>
#include <cstdint>
#include <cstddef>

#define B_N   16
#define A_N   8732
#define C_N   91
#define FG_N  90
#define K_TOP 400
#define D_N   200
#define NTASK (B_N * FG_N)   // 1440
#define K1_APB 128           // anchors per block in k1
#define K1_NBLK ((A_N + K1_APB - 1) / K1_APB)   // 69
#define K2_CAP 2048          // survivor list capacity (mean ~900, sigma ~28)

// ---------------------------------------------------------------------------
// K1: softmax + decode, LDS-staged (coalesced float4 slab load, expf once).
// ---------------------------------------------------------------------------
__global__ __launch_bounds__(128) void k1_softmax_decode(
    const float* __restrict__ cls, const float* __restrict__ reg,
    const float* __restrict__ anc, float* __restrict__ probs_t,
    float* __restrict__ boxes)
{
#pragma clang fp contract(off)
  __shared__ float4 lds4[(K1_APB * C_N + 3) / 4];   // 46.6 KB
  float* lds = (float*)lds4;
  const int bb = blockIdx.x;
  const int b = bb / K1_NBLK;
  const int blk = bb - b * K1_NBLK;
  const int a0 = blk * K1_APB;
  const int nloc = (A_N - a0) < K1_APB ? (A_N - a0) : K1_APB;
  const int tid = threadIdx.x;

  const size_t gbase_f4 = ((size_t)(b * A_N + a0) * C_N) >> 2;
  const size_t TOT_F4 = ((size_t)B_N * A_N * C_N) >> 2;
  const float4* cls4 = (const float4*)cls;
  constexpr int NF4 = (K1_APB * C_N) / 4;           // 2912
  for (int i = tid; i < NF4; i += K1_APB) {
    size_t g = gbase_f4 + i;
    if (g < TOT_F4) lds4[i] = cls4[g];
  }
  __syncthreads();

  if (tid >= nloc) return;
  const int a = a0 + tid;
  const int tg = b * A_N + a;
  float* lg = lds + tid * C_N;

  float m = lg[0];
  for (int c = 1; c < C_N; ++c) m = fmaxf(m, lg[c]);
  float s = 0.0f;
  for (int c = 0; c < C_N; ++c) {
    float e = expf(lg[c] - m);
    s += e;
    lg[c] = e;
  }
  for (int c = 1; c < C_N; ++c)
    probs_t[((size_t)b * FG_N + (c - 1)) * A_N + a] = lg[c] / s;

  float4 rl = *(const float4*)(reg + (size_t)tg * 4);
  float4 an = *(const float4*)(anc + (size_t)a * 4);
  float wa = an.z - an.x;
  float ha = an.w - an.y;
  float cxa = an.x + 0.5f * wa;
  float cya = an.y + 0.5f * ha;
  float dx = rl.x / 10.0f;
  float dy = rl.y / 10.0f;
  const float clipv = 4.135166556742356f;   // log(1000/16)
  float dw = fminf(rl.z / 5.0f, clipv);
  float dh = fminf(rl.w / 5.0f, clipv);
  float t1 = dx * wa;  float cx = t1 + cxa;
  float t2 = dy * ha;  float cy = t2 + cya;
  float w = expf(dw) * wa;
  float h = expf(dh) * ha;
  float4 out;
  out.x = fminf(fmaxf(cx - 0.5f * w, 0.0f), 300.0f);
  out.y = fminf(fmaxf(cy - 0.5f * h, 0.0f), 300.0f);
  out.z = fminf(fmaxf(cx + 0.5f * w, 0.0f), 300.0f);
  out.w = fminf(fmaxf(cy + 0.5f * h, 0.0f), 300.0f);
  *(float4*)(boxes + (size_t)tg * 4) = out;
}

// ---------------------------------------------------------------------------
// shared helper: descending rank-select over a 256-chunked histogram
// ---------------------------------------------------------------------------
__device__ __forceinline__ void scan_select(int* hist, int nbins, int need,
                                            int tid, int* chunk, int* res)
{
  int per = nbins >> 8;            // 4096 -> 16, 256 -> 1
  int s = 0;
  for (int i = 0; i < per; ++i) s += hist[tid * per + i];
  chunk[tid] = s;
  __syncthreads();
  if (tid == 0) {
    int cum = 0;
    for (int t2 = 255; t2 >= 0; --t2) { int v = chunk[t2]; chunk[t2] = cum; cum += v; }
  }
  __syncthreads();
  int cum = chunk[tid];            // count in strictly-higher chunks
  for (int i = per - 1; i >= 0; --i) {
    int bn = tid * per + i;
    int h = hist[bn];
    if (cum < need && need <= cum + h) { res[0] = bn; res[1] = cum; }
    cum += h;
  }
  __syncthreads();
}

// ---------------------------------------------------------------------------
// K2: exact top-400 per (image, fg-class) via histogram rank-scatter.
//     Survivor scores lie in (0.01, 1] -> float-bit slice [25:14] is a
//     monotone 12-bit bin (3 exp + 9 mantissa bits; top 5 exp bits constant).
//     One global pass collects survivors into LDS; 4096-bin histogram +
//     descending prefix gives each key its global rank base; scatter orders
//     by bin; tiny per-bin insertion sorts (avg ~1 el) restore exact
//     (score desc, anchor asc) order. No 55-phase bitonic. Exact legacy
//     radix+bitonic fallback for >2048 survivors / dropped needed element.
// ---------------------------------------------------------------------------
__global__ __launch_bounds__(256) void k2_topk(
    const float* __restrict__ probs_t, int* __restrict__ topk_anchor,
    float* __restrict__ topk_score, int* __restrict__ topk_cnt)
{
  __shared__ unsigned long long lst[K2_CAP];     // 16.4 KB
  __shared__ int hist[4096];                     // 16.4 KB (counts)
  __shared__ int cursor[4096];                   // 16.4 KB (base, then cursor)
  __shared__ unsigned long long sorted[1024];    //  8.2 KB
  __shared__ int chunk[256];
  __shared__ int res[2];
  __shared__ int s_lcnt;
  __shared__ int s_bad;
  const int task = blockIdx.x;
  const int tid = threadIdx.x;
  const float* sc = probs_t + (size_t)task * A_N;

  if (tid == 0) { s_lcnt = 0; s_bad = 0; }
  __syncthreads();
  // Pass 1: collect every candidate >0.01 (count exact; stores capped)
  for (int a = tid; a < A_N; a += 256) {
    float p = sc[a];
    if (p > 0.01f) {
      unsigned k = __float_as_uint(p);
      int pos = atomicAdd(&s_lcnt, 1);
      if (pos < K2_CAP)
        lst[pos] = ((unsigned long long)k << 32) | (unsigned)(0xFFFFFFFFu - (unsigned)a);
    }
  }
  __syncthreads();
  const int total = s_lcnt;
  const int ksel = total < K_TOP ? total : K_TOP;
  bool fast = (total <= K2_CAP);

  if (fast) {
    // histogram over monotone 12-bit bins
    for (int i = tid; i < 4096; i += 256) hist[i] = 0;
    __syncthreads();
    for (int i = tid; i < total; i += 256) {
      unsigned sb = (unsigned)(lst[i] >> 32);
      atomicAdd(&hist[(sb >> 14) & 0xFFFu], 1);
    }
    __syncthreads();
    // descending exclusive prefix -> cursor[bin] = #keys in higher bins
    {
      int s = 0;
      for (int i = 0; i < 16; ++i) s += hist[tid * 16 + i];
      chunk[tid] = s;
    }
    __syncthreads();
    if (tid == 0) {
      int run = 0;
      for (int c = 255; c >= 0; --c) { int v = chunk[c]; chunk[c] = run; run += v; }
    }
    __syncthreads();
    {
      int acc = chunk[tid];
      for (int i = 15; i >= 0; --i) {
        int bn = tid * 16 + i;
        cursor[bn] = acc;
        acc += hist[bn];
      }
    }
    __syncthreads();
    // scatter: rank-ordered by bin; positions >=1024 have rank >1024 > 400
    for (int i = tid; i < total; i += 256) {
      unsigned long long k = lst[i];
      int bn = (int)(((unsigned)(k >> 32) >> 14) & 0xFFFu);
      int pos = atomicAdd(&cursor[bn], 1);
      if (pos < 1024) sorted[pos] = k;
    }
    __syncthreads();
    // per-bin insertion sort (descending u64) for bins that can touch top-400
    for (int bn = tid * 16; bn < tid * 16 + 16; ++bn) {
      int cnt = hist[bn];
      if (cnt <= 0) continue;
      int end0 = cursor[bn];          // base + cnt
      int start = end0 - cnt;
      if (start >= K_TOP) continue;   // cannot affect top-400
      if (end0 > 1024) { s_bad = 1; continue; }   // dropped needed element
      for (int i = start + 1; i < end0; ++i) {
        unsigned long long v = sorted[i];
        int j = i - 1;
        while (j >= start && sorted[j] < v) { sorted[j + 1] = sorted[j]; --j; }
        sorted[j + 1] = v;
      }
    }
    __syncthreads();
    if (s_bad) fast = false;
  }

  if (fast) {
    for (int r = tid; r < K_TOP; r += 256) {
      int anchor = 0;
      float scv = -1.0f;
      if (r < ksel) {
        unsigned long long v = sorted[r];
        anchor = (int)(0xFFFFFFFFu - (unsigned)(v & 0xFFFFFFFFull));
        scv = __uint_as_float((unsigned)(v >> 32));
      }
      topk_anchor[(size_t)task * K_TOP + r] = anchor;
      topk_score[(size_t)task * K_TOP + r] = scv;
    }
    if (tid == 0) topk_cnt[task] = ksel;
    return;
  }

  // ---------- exact legacy fallback: radix select + bitonic 1024 ----------
  for (int i = tid; i < 4096; i += 256) hist[i] = 0;
  __syncthreads();
  for (int a = tid; a < A_N; a += 256) {
    float p = sc[a];
    if (p > 0.01f) atomicAdd(&hist[__float_as_uint(p) >> 20], 1);
  }
  __syncthreads();
  int need = K_TOP;
  scan_select(hist, 4096, need, tid, chunk, res);
  const unsigned b1 = (unsigned)res[0];
  const int above1 = res[1];
  const int in1 = hist[b1];
  __syncthreads();
  unsigned cutoff;
  if (above1 + in1 <= 1024) {
    cutoff = b1 << 20;
  } else {
    need -= above1;
    for (int i = tid; i < 4096; i += 256) hist[i] = 0;
    __syncthreads();
    for (int a = tid; a < A_N; a += 256) {
      float p = sc[a];
      if (p > 0.01f) {
        unsigned k = __float_as_uint(p);
        if ((k >> 20) == b1) atomicAdd(&hist[(k >> 8) & 0xFFFu], 1);
      }
    }
    __syncthreads();
    scan_select(hist, 4096, need, tid, chunk, res);
    const unsigned b2 = (unsigned)res[0];
    need -= res[1];
    const unsigned pre12 = (b1 << 12) | b2;
    __syncthreads();
    hist[tid] = 0;
    __syncthreads();
    for (int a = tid; a < A_N; a += 256) {
      float p = sc[a];
      if (p > 0.01f) {
        unsigned k = __float_as_uint(p);
        if ((k >> 8) == pre12) atomicAdd(&hist[k & 0xFFu], 1);
      }
    }
    __syncthreads();
    scan_select(hist, 256, need, tid, chunk, res);
    cutoff = (pre12 << 8) | (unsigned)res[0];
    __syncthreads();
  }
  if (tid == 0) s_lcnt = 0;
  __syncthreads();
  for (int a = tid; a < A_N; a += 256) {
    float p = sc[a];
    if (p > 0.01f) {
      unsigned k = __float_as_uint(p);
      if (k >= cutoff) {
        int pos = atomicAdd(&s_lcnt, 1);
        if (pos < 1024)
          lst[pos] = ((unsigned long long)k << 32) | (unsigned)(0xFFFFFFFFu - (unsigned)a);
      }
    }
  }
  __syncthreads();
  const int n = s_lcnt < 1024 ? s_lcnt : 1024;
  const int W = (n <= 512) ? 512 : 1024;
  for (int i = tid; i < W; i += 256) if (i >= n) lst[i] = 0ULL;
  __syncthreads();
  for (int kk = 2; kk <= W; kk <<= 1) {
    for (int jj = kk >> 1; jj > 0; jj >>= 1) {
      for (int i = tid; i < W; i += 256) {
        int ix = i ^ jj;
        if (ix > i) {
          unsigned long long va = lst[i], vb = lst[ix];
          bool desc = ((i & kk) == 0);
          if (desc ? (va < vb) : (va > vb)) { lst[i] = vb; lst[ix] = va; }
        }
      }
      __syncthreads();
    }
  }
  for (int r = tid; r < K_TOP; r += 256) {
    int anchor = 0;
    float scv = -1.0f;
    if (r < ksel) {
      unsigned long long v = lst[r];
      anchor = (int)(0xFFFFFFFFu - (unsigned)(v & 0xFFFFFFFFull));
      scv = __uint_as_float((unsigned)(v >> 32));
    }
    topk_anchor[(size_t)task * K_TOP + r] = anchor;
    topk_score[(size_t)task * K_TOP + r] = scv;
  }
  if (tid == 0) topk_cnt[task] = ksel;
}

// ---------------------------------------------------------------------------
// K3: chunked greedy NMS, one BLOCK (4 waves) per (image,class).
//     Kept-test strided over 4 waves; wave-uniform divide guard; resolve on
//     wave 0. Result identical to serial greedy; IoU bit-matches reference.
// ---------------------------------------------------------------------------
__global__ __launch_bounds__(256) void k3_nms(
    const float* __restrict__ boxes, const int* __restrict__ topk_anchor,
    const float* __restrict__ topk_score, const int* __restrict__ topk_cnt,
    unsigned long long* __restrict__ kept_key, int* __restrict__ kept_cnt)
{
#pragma clang fp contract(off)
  __shared__ float4 keptb[D_N];
  __shared__ float  kepta[D_N];
  __shared__ int    keptr[D_N];
  __shared__ unsigned long long s_supm[4];
  __shared__ int s_nk;
  const int task = blockIdx.x;
  const int wid  = threadIdx.x >> 6;
  const int lane = threadIdx.x & 63;
  const int b = task / FG_N;
  const int c = task - b * FG_N;
  const float off = (float)(c + 1) * 302.0f;
  const int cnt = topk_cnt[task];
  const int* ta = topk_anchor + (size_t)task * K_TOP;
  const float* ts = topk_score + (size_t)task * K_TOP;
  const float* bx = boxes + (size_t)b * (A_N * 4);

  if (threadIdx.x == 0) s_nk = 0;
  __syncthreads();

  float4 nxt = make_float4(0.0f, 0.0f, 0.0f, 0.0f);
  if (lane < cnt) nxt = *(const float4*)(bx + (size_t)ta[lane] * 4);

  for (int c0 = 0; c0 < cnt; c0 += 64) {
    float4 cur = nxt;
    int nidx = c0 + 64 + lane;
    if (nidx < cnt) nxt = *(const float4*)(bx + (size_t)ta[nidx] * 4);
    const bool validc = (c0 + lane) < cnt;
    cur.x += off; cur.y += off; cur.z += off; cur.w += off;
    const float area = (cur.z - cur.x) * (cur.w - cur.y);
    const int nk = s_nk;

    bool sup = !validc;
    for (int k = wid; k < nk; k += 4) {
      float4 kb = keptb[k];
      float  ka = kepta[k];
      float ix1 = fmaxf(cur.x, kb.x);
      float iy1 = fmaxf(cur.y, kb.y);
      float ix2 = fminf(cur.z, kb.z);
      float iy2 = fminf(cur.w, kb.w);
      float inter = fmaxf(ix2 - ix1, 0.0f) * fmaxf(iy2 - iy1, 0.0f);
      float denom = ka + area - inter + 1e-9f;
      float thr = 0.45f * denom;
      bool s_sup = inter > thr;
      bool amb = fabsf(inter - thr) <= 1.5e-6f * thr;
      if (__ballot(amb)) {
        if (amb) s_sup = (inter / denom) > 0.45f;
      }
      sup = sup || s_sup;
    }
    s_supm[wid] = __ballot(sup);
    __syncthreads();

    if (wid == 0) {
      unsigned long long todo =
          ~(s_supm[0] | s_supm[1] | s_supm[2] | s_supm[3]);
      unsigned long long surv = 0ULL;
      int ns = 0;
      const int room = D_N - nk;
      while (todo) {
        if (ns == room) break;
        int j = __ffsll((unsigned long long)todo) - 1;
        surv |= 1ULL << j;
        ++ns;
        todo &= ~(1ULL << j);
        float jx1 = __shfl(cur.x, j);
        float jy1 = __shfl(cur.y, j);
        float jx2 = __shfl(cur.z, j);
        float jy2 = __shfl(cur.w, j);
        float ja  = __shfl(area, j);
        float ix1 = fmaxf(jx1, cur.x);
        float iy1 = fmaxf(jy1, cur.y);
        float ix2 = fminf(jx2, cur.z);
        float iy2 = fminf(jy2, cur.w);
        float inter = fmaxf(ix2 - ix1, 0.0f) * fmaxf(iy2 - iy1, 0.0f);
        float denom = ja + area - inter + 1e-9f;
        float thr = 0.45f * denom;
        bool s_sup = inter > thr;
        bool amb = fabsf(inter - thr) <= 1.5e-6f * thr;
        if (__ballot(amb)) {
          if (amb) s_sup = (inter / denom) > 0.45f;
        }
        unsigned long long supj = __ballot(s_sup);
        supj &= ~(1ULL << j);
        todo &= ~supj;
      }
      if ((surv >> lane) & 1ULL) {
        int my = nk + __popcll(surv & ((1ULL << lane) - 1ULL));
        keptb[my] = cur;
        kepta[my] = area;
        keptr[my] = c0 + lane;
      }
      if (lane == 0) s_nk = nk + ns;
    }
    __syncthreads();
    if (s_nk >= D_N) break;
  }

  const int nkf = s_nk;
  for (int k = threadIdx.x; k < nkf; k += 256) {
    int r = keptr[k];
    unsigned sb = __float_as_uint(ts[r]);
    kept_key[(size_t)task * D_N + k] =
        ((unsigned long long)sb << 32) |
        (unsigned)(0xFFFFFFFFu - (unsigned)(c * K_TOP + r));
  }
  if (threadIdx.x == 0) kept_cnt[task] = nkf;
}

// ---------------------------------------------------------------------------
// K4: per-image global pick selection = parallel top-200 of survivor keys.
// ---------------------------------------------------------------------------
__global__ __launch_bounds__(256) void k4_sel(
    const unsigned long long* __restrict__ kept_key,
    const int* __restrict__ kept_cnt, int* __restrict__ pick_flat)
{
  __shared__ int hist[4096];
  __shared__ int chunk[256];
  __shared__ int res[2];
  __shared__ int s_lcnt;
  __shared__ int s_cnts[FG_N];
  __shared__ unsigned long long lst[1024];
  const int b = blockIdx.x;
  const int tid = threadIdx.x;
  const unsigned long long* kb = kept_key + (size_t)b * FG_N * D_N;

  if (tid < FG_N) s_cnts[tid] = kept_cnt[b * FG_N + tid];
  for (int i = tid; i < 4096; i += 256) hist[i] = 0;
  if (tid == 0) s_lcnt = 0;
  __syncthreads();

  for (int idx = tid; idx < FG_N * D_N; idx += 256) {
    int c = idx / D_N, r = idx - c * D_N;
    if (r < s_cnts[c]) {
      unsigned long long k = kb[idx];
      atomicAdd(&hist[(int)(k >> 52)], 1);
      atomicAdd(&s_lcnt, 1);
    }
  }
  __syncthreads();
  const int total = s_lcnt;
  const int npick = total < D_N ? total : D_N;
  unsigned cutoff32 = 1u;
  if (total > D_N) {
    int need = D_N;
    scan_select(hist, 4096, need, tid, chunk, res);
    const unsigned b1 = (unsigned)res[0];
    const int above1 = res[1];
    const int in1 = hist[b1];
    __syncthreads();
    if (above1 + in1 <= 1024) {
      cutoff32 = b1 << 20;
    } else {
      need -= above1;
      for (int i = tid; i < 4096; i += 256) hist[i] = 0;
      __syncthreads();
      for (int idx = tid; idx < FG_N * D_N; idx += 256) {
        int c = idx / D_N, r = idx - c * D_N;
        if (r < s_cnts[c]) {
          unsigned long long k = kb[idx];
          if ((unsigned)(k >> 52) == b1)
            atomicAdd(&hist[(int)((k >> 40) & 0xFFFull)], 1);
        }
      }
      __syncthreads();
      scan_select(hist, 4096, need, tid, chunk, res);
      const unsigned b2 = (unsigned)res[0];
      need -= res[1];
      const unsigned pre12 = (b1 << 12) | b2;
      __syncthreads();
      hist[tid] = 0;
      __syncthreads();
      for (int idx = tid; idx < FG_N * D_N; idx += 256) {
        int c = idx / D_N, r = idx - c * D_N;
        if (r < s_cnts[c]) {
          unsigned long long k = kb[idx];
          if ((unsigned)(k >> 40) == pre12)
            atomicAdd(&hist[(int)((k >> 32) & 0xFFull)], 1);
        }
      }
      __syncthreads();
      scan_select(hist, 256, need, tid, chunk, res);
      cutoff32 = (pre12 << 8) | (unsigned)res[0];
      __syncthreads();
    }
  }
  if (tid == 0) s_lcnt = 0;
  __syncthreads();
  const unsigned long long cutkey = (unsigned long long)cutoff32 << 32;
  for (int idx = tid; idx < FG_N * D_N; idx += 256) {
    int c = idx / D_N, r = idx - c * D_N;
    if (r < s_cnts[c]) {
      unsigned long long k = kb[idx];
      if (k >= cutkey) {
        int pos = atomicAdd(&s_lcnt, 1);
        if (pos < 1024) lst[pos] = k;
      }
    }
  }
  __syncthreads();
  const int n = s_lcnt < 1024 ? s_lcnt : 1024;
  const int W = (n <= 256) ? 256 : (n <= 512) ? 512 : 1024;
  for (int i = tid; i < W; i += 256) if (i >= n) lst[i] = 0ULL;
  __syncthreads();
  for (int kk = 2; kk <= W; kk <<= 1) {
    for (int jj = kk >> 1; jj > 0; jj >>= 1) {
      for (int i = tid; i < W; i += 256) {
        int ix = i ^ jj;
        if (ix > i) {
          unsigned long long va = lst[i], vb = lst[ix];
          bool desc = ((i & kk) == 0);
          if (desc ? (va < vb) : (va > vb)) { lst[i] = vb; lst[ix] = va; }
        }
      }
      __syncthreads();
    }
  }
  for (int i = tid; i < D_N; i += 256) {
    int v = -1;
    if (i < npick)
      v = (int)(0xFFFFFFFFu - (unsigned)(lst[i] & 0xFFFFFFFFull));
    pick_flat[b * D_N + i] = v;
  }
}

// ---------------------------------------------------------------------------
// K5: one wave per pick; packed u64 butterfly top-2 over 90 classes.
// ---------------------------------------------------------------------------
__global__ __launch_bounds__(256) void k5_out(
    const float* __restrict__ probs_t, const float* __restrict__ boxes,
    const int* __restrict__ topk_anchor, const int* __restrict__ pick_flat,
    float* __restrict__ out)
{
  const int wid  = threadIdx.x >> 6;
  const int lane = threadIdx.x & 63;
  const int pick = blockIdx.x * 4 + wid;
  const int b = pick / D_N;
  float* ob = out + (size_t)pick * 4;
  float* os = out + (size_t)B_N * D_N * 4 + (size_t)pick * 2;
  float* ol = out + (size_t)B_N * D_N * 6 + (size_t)pick * 2;
  const int flat = pick_flat[pick];
  if (flat < 0) {
    if (lane == 0) {
      ob[0] = 0.0f; ob[1] = 0.0f; ob[2] = 0.0f; ob[3] = 0.0f;
      os[0] = 0.0f; os[1] = 0.0f;
      ol[0] = 0.0f; ol[1] = 0.0f;
    }
    return;
  }
  const int c = flat / K_TOP;
  const int r = flat - c * K_TOP;
  const int anchor = topk_anchor[((size_t)b * FG_N + c) * K_TOP + r];
  const float* pp = probs_t + (size_t)b * FG_N * A_N + anchor;

  unsigned long long hi, lo = 0ULL;
  {
    float p = pp[(size_t)lane * A_N];
    hi = ((unsigned long long)__float_as_uint(p) << 32) | (0xFFFFFFFFu - (unsigned)lane);
  }
  if (lane + 64 < FG_N) {
    float p = pp[(size_t)(lane + 64) * A_N];
    unsigned long long k2 = ((unsigned long long)__float_as_uint(p) << 32) |
                            (0xFFFFFFFFu - (unsigned)(lane + 64));
    if (k2 > hi) { lo = hi; hi = k2; } else lo = k2;
  }
#pragma unroll
  for (int d = 1; d < 64; d <<= 1) {
    unsigned long long oh = __shfl_xor(hi, d, 64);
    unsigned long long ol2 = __shfl_xor(lo, d, 64);
    unsigned long long nh = hi > oh ? hi : oh;
    unsigned long long mn = hi > oh ? oh : hi;
    unsigned long long ml = lo > ol2 ? lo : ol2;
    hi = nh;
    lo = mn > ml ? mn : ml;
  }
  if (lane == 0) {
    float4 bp = *(const float4*)(boxes + ((size_t)b * A_N + anchor) * 4);
    *(float4*)ob = bp;
    unsigned cc1 = 0xFFFFFFFFu - (unsigned)(hi & 0xFFFFFFFFull);
    unsigned cc2 = 0xFFFFFFFFu - (unsigned)(lo & 0xFFFFFFFFull);
    os[0] = __uint_as_float((unsigned)(hi >> 32));
    os[1] = __uint_as_float((unsigned)(lo >> 32));
    ol[0] = (float)(cc1 + 1);
    ol[1] = (float)(cc2 + 1);
  }
}

// ---------------------------------------------------------------------------
extern "C" void kernel_launch(void* const* d_in, const int* in_sizes, int n_in,
                              void* d_out, int out_size, void* d_ws, size_t ws_size,
                              hipStream_t stream)
{
  (void)in_sizes; (void)n_in; (void)out_size; (void)ws_size;
  const float* cls = (const float*)d_in[0];
  const float* reg = (const float*)d_in[1];
  const float* anc = (const float*)d_in[2];

  char* w = (char*)d_ws;
  size_t off = 0;
  auto carve = [&](size_t bytes) -> char* {
    char* p = w + off;
    off += (bytes + 255) & ~(size_t)255;
    return p;
  };
  float* probs_t                = (float*)carve((size_t)B_N * FG_N * A_N * 4);
  float* boxes                  = (float*)carve((size_t)B_N * A_N * 4 * 4);
  int* topk_anchor              = (int*)carve((size_t)NTASK * K_TOP * 4);
  float* topk_score             = (float*)carve((size_t)NTASK * K_TOP * 4);
  int* topk_cnt                 = (int*)carve((size_t)NTASK * 4);
  unsigned long long* kept_key  = (unsigned long long*)carve((size_t)NTASK * D_N * 8);
  int* kept_cnt                 = (int*)carve((size_t)NTASK * 4);
  int* pick_flat                = (int*)carve((size_t)B_N * D_N * 4);

  hipLaunchKernelGGL(k1_softmax_decode, dim3(B_N * K1_NBLK), dim3(K1_APB), 0, stream,
                     cls, reg, anc, probs_t, boxes);
  hipLaunchKernelGGL(k2_topk, dim3(NTASK), dim3(256), 0, stream,
                     probs_t, topk_anchor, topk_score, topk_cnt);
  hipLaunchKernelGGL(k3_nms, dim3(NTASK), dim3(256), 0, stream,
                     boxes, topk_anchor, topk_score, topk_cnt, kept_key, kept_cnt);
  hipLaunchKernelGGL(k4_sel, dim3(B_N), dim3(256), 0, stream,
                     kept_key, kept_cnt, pick_flat);
  hipLaunchKernelGGL(k5_out, dim3(B_N * D_N / 4), dim3(256), 0, stream,
                     probs_t, boxes, topk_anchor, pick_flat, (float*)d_out);
}

// Round 9
// 329.541 us; speedup vs baseline: 1.3428x; 1.3428x over previous
//
#include <hip/hip_runtime.h>
#include <cstdint>
#include <cstddef>

#define B_N   16
#define A_N   8732
#define C_N   91
#define FG_N  90
#define K_TOP 400
#define D_N   200
#define NTASK (B_N * FG_N)   // 1440
#define K1_APB 128           // anchors per block in k1
#define K1_NBLK ((A_N + K1_APB - 1) / K1_APB)   // 69

// ---------------------------------------------------------------------------
// K1: softmax + decode, LDS-staged (coalesced float4 slab load, expf once).
// ---------------------------------------------------------------------------
__global__ __launch_bounds__(128) void k1_softmax_decode(
    const float* __restrict__ cls, const float* __restrict__ reg,
    const float* __restrict__ anc, float* __restrict__ probs_t,
    float* __restrict__ boxes)
{
#pragma clang fp contract(off)
  __shared__ float4 lds4[(K1_APB * C_N + 3) / 4];   // 46.6 KB
  float* lds = (float*)lds4;
  const int bb = blockIdx.x;
  const int b = bb / K1_NBLK;
  const int blk = bb - b * K1_NBLK;
  const int a0 = blk * K1_APB;
  const int nloc = (A_N - a0) < K1_APB ? (A_N - a0) : K1_APB;
  const int tid = threadIdx.x;

  const size_t gbase_f4 = ((size_t)(b * A_N + a0) * C_N) >> 2;
  const size_t TOT_F4 = ((size_t)B_N * A_N * C_N) >> 2;
  const float4* cls4 = (const float4*)cls;
  constexpr int NF4 = (K1_APB * C_N) / 4;           // 2912
  for (int i = tid; i < NF4; i += K1_APB) {
    size_t g = gbase_f4 + i;
    if (g < TOT_F4) lds4[i] = cls4[g];
  }
  __syncthreads();

  if (tid >= nloc) return;
  const int a = a0 + tid;
  const int tg = b * A_N + a;
  float* lg = lds + tid * C_N;

  float m = lg[0];
  for (int c = 1; c < C_N; ++c) m = fmaxf(m, lg[c]);
  float s = 0.0f;
  for (int c = 0; c < C_N; ++c) {
    float e = expf(lg[c] - m);
    s += e;
    lg[c] = e;
  }
  for (int c = 1; c < C_N; ++c)
    probs_t[((size_t)b * FG_N + (c - 1)) * A_N + a] = lg[c] / s;

  float4 rl = *(const float4*)(reg + (size_t)tg * 4);
  float4 an = *(const float4*)(anc + (size_t)a * 4);
  float wa = an.z - an.x;
  float ha = an.w - an.y;
  float cxa = an.x + 0.5f * wa;
  float cya = an.y + 0.5f * ha;
  float dx = rl.x / 10.0f;
  float dy = rl.y / 10.0f;
  const float clipv = 4.135166556742356f;   // log(1000/16)
  float dw = fminf(rl.z / 5.0f, clipv);
  float dh = fminf(rl.w / 5.0f, clipv);
  float t1 = dx * wa;  float cx = t1 + cxa;
  float t2 = dy * ha;  float cy = t2 + cya;
  float w = expf(dw) * wa;
  float h = expf(dh) * ha;
  float4 out;
  out.x = fminf(fmaxf(cx - 0.5f * w, 0.0f), 300.0f);
  out.y = fminf(fmaxf(cy - 0.5f * h, 0.0f), 300.0f);
  out.z = fminf(fmaxf(cx + 0.5f * w, 0.0f), 300.0f);
  out.w = fminf(fmaxf(cy + 0.5f * h, 0.0f), 300.0f);
  *(float4*)(boxes + (size_t)tg * 4) = out;
}

// ---------------------------------------------------------------------------
// shared helper: descending rank-select over a 256-chunked histogram
// ---------------------------------------------------------------------------
__device__ __forceinline__ void scan_select(int* hist, int nbins, int need,
                                            int tid, int* chunk, int* res)
{
  int per = nbins >> 8;            // 4096 -> 16, 256 -> 1
  int s = 0;
  for (int i = 0; i < per; ++i) s += hist[tid * per + i];
  chunk[tid] = s;
  __syncthreads();
  if (tid == 0) {
    int cum = 0;
    for (int t2 = 255; t2 >= 0; --t2) { int v = chunk[t2]; chunk[t2] = cum; cum += v; }
  }
  __syncthreads();
  int cum = chunk[tid];            // count in strictly-higher chunks
  for (int i = per - 1; i >= 0; --i) {
    int bn = tid * per + i;
    int h = hist[bn];
    if (cum < need && need <= cum + h) { res[0] = bn; res[1] = cum; }
    cum += h;
  }
  __syncthreads();
}

// ---------------------------------------------------------------------------
// K2: exact top-400 per (image, fg-class) via low-LDS histogram rank-scatter.
//     Survivor scores lie in (0.01, 1] -> float-bit slice [25:14] is a
//     monotone 12-bit bin (top 6 bits constant). Pass A: global read ->
//     4096-bin histogram. In-place descending exclusive prefix -> bases.
//     Pass B: global re-read (L1/L2-resident) -> scatter to rank position.
//     start/end of each bin recovered from post-scatter cursors (no second
//     array). Tiny per-bin insertion sorts restore exact (score desc,
//     anchor asc) order. ~8 barriers, ~25.5 KB LDS (6 blocks/CU).
//     Exact legacy radix+bitonic fallback (same LDS) if a needed bin
//     straddles slot 1024 (requires >624 keys sharing 21 high bits).
// ---------------------------------------------------------------------------
__global__ __launch_bounds__(256) void k2_topk(
    const float* __restrict__ probs_t, int* __restrict__ topk_anchor,
    float* __restrict__ topk_score, int* __restrict__ topk_cnt)
{
  __shared__ int cnt[4096];                      // 16.4 KB: counts->bases->ends
  __shared__ unsigned long long sorted[1024];    //  8.2 KB
  __shared__ int chunk[256];                     //  1 KB
  __shared__ int res[2];
  __shared__ int s_total;
  __shared__ int s_bad;
  __shared__ int s_lcnt;
  const int task = blockIdx.x;
  const int tid = threadIdx.x;
  const float* sc = probs_t + (size_t)task * A_N;

  for (int i = tid; i < 4096; i += 256) cnt[i] = 0;
  if (tid == 0) s_bad = 0;
  __syncthreads();

  // Pass A: histogram over monotone 12-bit bins
  for (int a = tid; a < A_N; a += 256) {
    float p = sc[a];
    if (p > 0.01f)
      atomicAdd(&cnt[(__float_as_uint(p) >> 14) & 0xFFFu], 1);
  }
  __syncthreads();
  // in-place descending exclusive prefix (thread owns bins [tid*16, +16))
  {
    int s = 0;
    for (int i = 0; i < 16; ++i) s += cnt[tid * 16 + i];
    chunk[tid] = s;
  }
  __syncthreads();
  if (tid == 0) {
    int run = 0;
    for (int c = 255; c >= 0; --c) { int v = chunk[c]; chunk[c] = run; run += v; }
    s_total = run;
  }
  __syncthreads();
  {
    int acc = chunk[tid];
    for (int i = 15; i >= 0; --i) {
      int bn = tid * 16 + i;
      int h = cnt[bn];
      cnt[bn] = acc;                 // base = #keys in strictly-higher bins
      acc += h;
    }
  }
  __syncthreads();
  const int total = s_total;
  const int ksel = total < K_TOP ? total : K_TOP;

  // Pass B: scatter to global rank position (re-read is L1/L2-resident)
  for (int a = tid; a < A_N; a += 256) {
    float p = sc[a];
    if (p > 0.01f) {
      unsigned k = __float_as_uint(p);
      int pos = atomicAdd(&cnt[(k >> 14) & 0xFFFu], 1);
      if (pos < 1024)
        sorted[pos] = ((unsigned long long)k << 32) | (unsigned)(0xFFFFFFFFu - (unsigned)a);
    }
  }
  __syncthreads();
  // per-bin insertion sort for bins that can touch top-400.
  // post-scatter: cnt[bn] = end[bn]; start[bn] = cnt[bn+1] (end of the
  // next-higher bin == this bin's base); start[4095] = 0.
  for (int i = 0; i < 16; ++i) {
    int bn = tid * 16 + i;
    int end0 = cnt[bn];
    int start = (bn < 4095) ? cnt[bn + 1] : 0;
    int cb = end0 - start;
    if (cb > 1 && start < K_TOP) {
      if (end0 > 1024) { s_bad = 1; continue; }
      for (int q = start + 1; q < end0; ++q) {
        unsigned long long v = sorted[q];
        int j = q - 1;
        while (j >= start && sorted[j] < v) { sorted[j + 1] = sorted[j]; --j; }
        sorted[j + 1] = v;
      }
    }
  }
  __syncthreads();

  if (s_bad) {
    // ---------- exact legacy fallback: radix select + bitonic 1024 ----------
    for (int i = tid; i < 4096; i += 256) cnt[i] = 0;
    __syncthreads();
    for (int a = tid; a < A_N; a += 256) {
      float p = sc[a];
      if (p > 0.01f) atomicAdd(&cnt[__float_as_uint(p) >> 20], 1);
    }
    __syncthreads();
    int need = K_TOP;
    scan_select(cnt, 4096, need, tid, chunk, res);
    const unsigned b1 = (unsigned)res[0];
    const int above1 = res[1];
    const int in1 = cnt[b1];
    __syncthreads();
    unsigned cutoff;
    if (above1 + in1 <= 1024) {
      cutoff = b1 << 20;
    } else {
      need -= above1;
      for (int i = tid; i < 4096; i += 256) cnt[i] = 0;
      __syncthreads();
      for (int a = tid; a < A_N; a += 256) {
        float p = sc[a];
        if (p > 0.01f) {
          unsigned k = __float_as_uint(p);
          if ((k >> 20) == b1) atomicAdd(&cnt[(k >> 8) & 0xFFFu], 1);
        }
      }
      __syncthreads();
      scan_select(cnt, 4096, need, tid, chunk, res);
      const unsigned b2 = (unsigned)res[0];
      need -= res[1];
      const unsigned pre12 = (b1 << 12) | b2;
      __syncthreads();
      cnt[tid] = 0;
      __syncthreads();
      for (int a = tid; a < A_N; a += 256) {
        float p = sc[a];
        if (p > 0.01f) {
          unsigned k = __float_as_uint(p);
          if ((k >> 8) == pre12) atomicAdd(&cnt[k & 0xFFu], 1);
        }
      }
      __syncthreads();
      scan_select(cnt, 256, need, tid, chunk, res);
      cutoff = (pre12 << 8) | (unsigned)res[0];
      __syncthreads();
    }
    if (tid == 0) s_lcnt = 0;
    __syncthreads();
    for (int a = tid; a < A_N; a += 256) {
      float p = sc[a];
      if (p > 0.01f) {
        unsigned k = __float_as_uint(p);
        if (k >= cutoff) {
          int pos = atomicAdd(&s_lcnt, 1);
          if (pos < 1024)
            sorted[pos] = ((unsigned long long)k << 32) | (unsigned)(0xFFFFFFFFu - (unsigned)a);
        }
      }
    }
    __syncthreads();
    const int n = s_lcnt < 1024 ? s_lcnt : 1024;
    const int W = (n <= 512) ? 512 : 1024;
    for (int i = tid; i < W; i += 256) if (i >= n) sorted[i] = 0ULL;
    __syncthreads();
    for (int kk = 2; kk <= W; kk <<= 1) {
      for (int jj = kk >> 1; jj > 0; jj >>= 1) {
        for (int i = tid; i < W; i += 256) {
          int ix = i ^ jj;
          if (ix > i) {
            unsigned long long va = sorted[i], vb = sorted[ix];
            bool desc = ((i & kk) == 0);
            if (desc ? (va < vb) : (va > vb)) { sorted[i] = vb; sorted[ix] = va; }
          }
        }
        __syncthreads();
      }
    }
  }

  for (int r = tid; r < K_TOP; r += 256) {
    int anchor = 0;
    float scv = -1.0f;
    if (r < ksel) {
      unsigned long long v = sorted[r];
      anchor = (int)(0xFFFFFFFFu - (unsigned)(v & 0xFFFFFFFFull));
      scv = __uint_as_float((unsigned)(v >> 32));
    }
    topk_anchor[(size_t)task * K_TOP + r] = anchor;
    topk_score[(size_t)task * K_TOP + r] = scv;
  }
  if (tid == 0) topk_cnt[task] = ksel;
}

// ---------------------------------------------------------------------------
// K3: chunked greedy NMS, one BLOCK (4 waves) per (image,class).
//     Kept-test strided over 4 waves; wave-uniform divide guard; resolve on
//     wave 0. Result identical to serial greedy; IoU bit-matches reference.
// ---------------------------------------------------------------------------
__global__ __launch_bounds__(256) void k3_nms(
    const float* __restrict__ boxes, const int* __restrict__ topk_anchor,
    const float* __restrict__ topk_score, const int* __restrict__ topk_cnt,
    unsigned long long* __restrict__ kept_key, int* __restrict__ kept_cnt)
{
#pragma clang fp contract(off)
  __shared__ float4 keptb[D_N];
  __shared__ float  kepta[D_N];
  __shared__ int    keptr[D_N];
  __shared__ unsigned long long s_supm[4];
  __shared__ int s_nk;
  const int task = blockIdx.x;
  const int wid  = threadIdx.x >> 6;
  const int lane = threadIdx.x & 63;
  const int b = task / FG_N;
  const int c = task - b * FG_N;
  const float off = (float)(c + 1) * 302.0f;
  const int cnt = topk_cnt[task];
  const int* ta = topk_anchor + (size_t)task * K_TOP;
  const float* ts = topk_score + (size_t)task * K_TOP;
  const float* bx = boxes + (size_t)b * (A_N * 4);

  if (threadIdx.x == 0) s_nk = 0;
  __syncthreads();

  float4 nxt = make_float4(0.0f, 0.0f, 0.0f, 0.0f);
  if (lane < cnt) nxt = *(const float4*)(bx + (size_t)ta[lane] * 4);

  for (int c0 = 0; c0 < cnt; c0 += 64) {
    float4 cur = nxt;
    int nidx = c0 + 64 + lane;
    if (nidx < cnt) nxt = *(const float4*)(bx + (size_t)ta[nidx] * 4);
    const bool validc = (c0 + lane) < cnt;
    cur.x += off; cur.y += off; cur.z += off; cur.w += off;
    const float area = (cur.z - cur.x) * (cur.w - cur.y);
    const int nk = s_nk;

    bool sup = !validc;
    for (int k = wid; k < nk; k += 4) {
      float4 kb = keptb[k];
      float  ka = kepta[k];
      float ix1 = fmaxf(cur.x, kb.x);
      float iy1 = fmaxf(cur.y, kb.y);
      float ix2 = fminf(cur.z, kb.z);
      float iy2 = fminf(cur.w, kb.w);
      float inter = fmaxf(ix2 - ix1, 0.0f) * fmaxf(iy2 - iy1, 0.0f);
      float denom = ka + area - inter + 1e-9f;
      float thr = 0.45f * denom;
      bool s_sup = inter > thr;
      bool amb = fabsf(inter - thr) <= 1.5e-6f * thr;
      if (__ballot(amb)) {
        if (amb) s_sup = (inter / denom) > 0.45f;
      }
      sup = sup || s_sup;
    }
    s_supm[wid] = __ballot(sup);
    __syncthreads();

    if (wid == 0) {
      unsigned long long todo =
          ~(s_supm[0] | s_supm[1] | s_supm[2] | s_supm[3]);
      unsigned long long surv = 0ULL;
      int ns = 0;
      const int room = D_N - nk;
      while (todo) {
        if (ns == room) break;
        int j = __ffsll((unsigned long long)todo) - 1;
        surv |= 1ULL << j;
        ++ns;
        todo &= ~(1ULL << j);
        float jx1 = __shfl(cur.x, j);
        float jy1 = __shfl(cur.y, j);
        float jx2 = __shfl(cur.z, j);
        float jy2 = __shfl(cur.w, j);
        float ja  = __shfl(area, j);
        float ix1 = fmaxf(jx1, cur.x);
        float iy1 = fmaxf(jy1, cur.y);
        float ix2 = fminf(jx2, cur.z);
        float iy2 = fminf(jy2, cur.w);
        float inter = fmaxf(ix2 - ix1, 0.0f) * fmaxf(iy2 - iy1, 0.0f);
        float denom = ja + area - inter + 1e-9f;
        float thr = 0.45f * denom;
        bool s_sup = inter > thr;
        bool amb = fabsf(inter - thr) <= 1.5e-6f * thr;
        if (__ballot(amb)) {
          if (amb) s_sup = (inter / denom) > 0.45f;
        }
        unsigned long long supj = __ballot(s_sup);
        supj &= ~(1ULL << j);
        todo &= ~supj;
      }
      if ((surv >> lane) & 1ULL) {
        int my = nk + __popcll(surv & ((1ULL << lane) - 1ULL));
        keptb[my] = cur;
        kepta[my] = area;
        keptr[my] = c0 + lane;
      }
      if (lane == 0) s_nk = nk + ns;
    }
    __syncthreads();
    if (s_nk >= D_N) break;
  }

  const int nkf = s_nk;
  for (int k = threadIdx.x; k < nkf; k += 256) {
    int r = keptr[k];
    unsigned sb = __float_as_uint(ts[r]);
    kept_key[(size_t)task * D_N + k] =
        ((unsigned long long)sb << 32) |
        (unsigned)(0xFFFFFFFFu - (unsigned)(c * K_TOP + r));
  }
  if (threadIdx.x == 0) kept_cnt[task] = nkf;
}

// ---------------------------------------------------------------------------
// K4: per-image global pick selection = parallel top-200 of survivor keys.
// ---------------------------------------------------------------------------
__global__ __launch_bounds__(256) void k4_sel(
    const unsigned long long* __restrict__ kept_key,
    const int* __restrict__ kept_cnt, int* __restrict__ pick_flat)
{
  __shared__ int hist[4096];
  __shared__ int chunk[256];
  __shared__ int res[2];
  __shared__ int s_lcnt;
  __shared__ int s_cnts[FG_N];
  __shared__ unsigned long long lst[1024];
  const int b = blockIdx.x;
  const int tid = threadIdx.x;
  const unsigned long long* kb = kept_key + (size_t)b * FG_N * D_N;

  if (tid < FG_N) s_cnts[tid] = kept_cnt[b * FG_N + tid];
  for (int i = tid; i < 4096; i += 256) hist[i] = 0;
  if (tid == 0) s_lcnt = 0;
  __syncthreads();

  for (int idx = tid; idx < FG_N * D_N; idx += 256) {
    int c = idx / D_N, r = idx - c * D_N;
    if (r < s_cnts[c]) {
      unsigned long long k = kb[idx];
      atomicAdd(&hist[(int)(k >> 52)], 1);
      atomicAdd(&s_lcnt, 1);
    }
  }
  __syncthreads();
  const int total = s_lcnt;
  const int npick = total < D_N ? total : D_N;
  unsigned cutoff32 = 1u;
  if (total > D_N) {
    int need = D_N;
    scan_select(hist, 4096, need, tid, chunk, res);
    const unsigned b1 = (unsigned)res[0];
    const int above1 = res[1];
    const int in1 = hist[b1];
    __syncthreads();
    if (above1 + in1 <= 1024) {
      cutoff32 = b1 << 20;
    } else {
      need -= above1;
      for (int i = tid; i < 4096; i += 256) hist[i] = 0;
      __syncthreads();
      for (int idx = tid; idx < FG_N * D_N; idx += 256) {
        int c = idx / D_N, r = idx - c * D_N;
        if (r < s_cnts[c]) {
          unsigned long long k = kb[idx];
          if ((unsigned)(k >> 52) == b1)
            atomicAdd(&hist[(int)((k >> 40) & 0xFFFull)], 1);
        }
      }
      __syncthreads();
      scan_select(hist, 4096, need, tid, chunk, res);
      const unsigned b2 = (unsigned)res[0];
      need -= res[1];
      const unsigned pre12 = (b1 << 12) | b2;
      __syncthreads();
      hist[tid] = 0;
      __syncthreads();
      for (int idx = tid; idx < FG_N * D_N; idx += 256) {
        int c = idx / D_N, r = idx - c * D_N;
        if (r < s_cnts[c]) {
          unsigned long long k = kb[idx];
          if ((unsigned)(k >> 40) == pre12)
            atomicAdd(&hist[(int)((k >> 32) & 0xFFull)], 1);
        }
      }
      __syncthreads();
      scan_select(hist, 256, need, tid, chunk, res);
      cutoff32 = (pre12 << 8) | (unsigned)res[0];
      __syncthreads();
    }
  }
  if (tid == 0) s_lcnt = 0;
  __syncthreads();
  const unsigned long long cutkey = (unsigned long long)cutoff32 << 32;
  for (int idx = tid; idx < FG_N * D_N; idx += 256) {
    int c = idx / D_N, r = idx - c * D_N;
    if (r < s_cnts[c]) {
      unsigned long long k = kb[idx];
      if (k >= cutkey) {
        int pos = atomicAdd(&s_lcnt, 1);
        if (pos < 1024) lst[pos] = k;
      }
    }
  }
  __syncthreads();
  const int n = s_lcnt < 1024 ? s_lcnt : 1024;
  const int W = (n <= 256) ? 256 : (n <= 512) ? 512 : 1024;
  for (int i = tid; i < W; i += 256) if (i >= n) lst[i] = 0ULL;
  __syncthreads();
  for (int kk = 2; kk <= W; kk <<= 1) {
    for (int jj = kk >> 1; jj > 0; jj >>= 1) {
      for (int i = tid; i < W; i += 256) {
        int ix = i ^ jj;
        if (ix > i) {
          unsigned long long va = lst[i], vb = lst[ix];
          bool desc = ((i & kk) == 0);
          if (desc ? (va < vb) : (va > vb)) { lst[i] = vb; lst[ix] = va; }
        }
      }
      __syncthreads();
    }
  }
  for (int i = tid; i < D_N; i += 256) {
    int v = -1;
    if (i < npick)
      v = (int)(0xFFFFFFFFu - (unsigned)(lst[i] & 0xFFFFFFFFull));
    pick_flat[b * D_N + i] = v;
  }
}

// ---------------------------------------------------------------------------
// K5: one wave per pick; packed u64 butterfly top-2 over 90 classes.
// ---------------------------------------------------------------------------
__global__ __launch_bounds__(256) void k5_out(
    const float* __restrict__ probs_t, const float* __restrict__ boxes,
    const int* __restrict__ topk_anchor, const int* __restrict__ pick_flat,
    float* __restrict__ out)
{
  const int wid  = threadIdx.x >> 6;
  const int lane = threadIdx.x & 63;
  const int pick = blockIdx.x * 4 + wid;
  const int b = pick / D_N;
  float* ob = out + (size_t)pick * 4;
  float* os = out + (size_t)B_N * D_N * 4 + (size_t)pick * 2;
  float* ol = out + (size_t)B_N * D_N * 6 + (size_t)pick * 2;
  const int flat = pick_flat[pick];
  if (flat < 0) {
    if (lane == 0) {
      ob[0] = 0.0f; ob[1] = 0.0f; ob[2] = 0.0f; ob[3] = 0.0f;
      os[0] = 0.0f; os[1] = 0.0f;
      ol[0] = 0.0f; ol[1] = 0.0f;
    }
    return;
  }
  const int c = flat / K_TOP;
  const int r = flat - c * K_TOP;
  const int anchor = topk_anchor[((size_t)b * FG_N + c) * K_TOP + r];
  const float* pp = probs_t + (size_t)b * FG_N * A_N + anchor;

  unsigned long long hi, lo = 0ULL;
  {
    float p = pp[(size_t)lane * A_N];
    hi = ((unsigned long long)__float_as_uint(p) << 32) | (0xFFFFFFFFu - (unsigned)lane);
  }
  if (lane + 64 < FG_N) {
    float p = pp[(size_t)(lane + 64) * A_N];
    unsigned long long k2 = ((unsigned long long)__float_as_uint(p) << 32) |
                            (0xFFFFFFFFu - (unsigned)(lane + 64));
    if (k2 > hi) { lo = hi; hi = k2; } else lo = k2;
  }
#pragma unroll
  for (int d = 1; d < 64; d <<= 1) {
    unsigned long long oh = __shfl_xor(hi, d, 64);
    unsigned long long ol2 = __shfl_xor(lo, d, 64);
    unsigned long long nh = hi > oh ? hi : oh;
    unsigned long long mn = hi > oh ? oh : hi;
    unsigned long long ml = lo > ol2 ? lo : ol2;
    hi = nh;
    lo = mn > ml ? mn : ml;
  }
  if (lane == 0) {
    float4 bp = *(const float4*)(boxes + ((size_t)b * A_N + anchor) * 4);
    *(float4*)ob = bp;
    unsigned cc1 = 0xFFFFFFFFu - (unsigned)(hi & 0xFFFFFFFFull);
    unsigned cc2 = 0xFFFFFFFFu - (unsigned)(lo & 0xFFFFFFFFull);
    os[0] = __uint_as_float((unsigned)(hi >> 32));
    os[1] = __uint_as_float((unsigned)(lo >> 32));
    ol[0] = (float)(cc1 + 1);
    ol[1] = (float)(cc2 + 1);
  }
}

// ---------------------------------------------------------------------------
extern "C" void kernel_launch(void* const* d_in, const int* in_sizes, int n_in,
                              void* d_out, int out_size, void* d_ws, size_t ws_size,
                              hipStream_t stream)
{
  (void)in_sizes; (void)n_in; (void)out_size; (void)ws_size;
  const float* cls = (const float*)d_in[0];
  const float* reg = (const float*)d_in[1];
  const float* anc = (const float*)d_in[2];

  char* w = (char*)d_ws;
  size_t off = 0;
  auto carve = [&](size_t bytes) -> char* {
    char* p = w + off;
    off += (bytes + 255) & ~(size_t)255;
    return p;
  };
  float* probs_t                = (float*)carve((size_t)B_N * FG_N * A_N * 4);
  float* boxes                  = (float*)carve((size_t)B_N * A_N * 4 * 4);
  int* topk_anchor              = (int*)carve((size_t)NTASK * K_TOP * 4);
  float* topk_score             = (float*)carve((size_t)NTASK * K_TOP * 4);
  int* topk_cnt                 = (int*)carve((size_t)NTASK * 4);
  unsigned long long* kept_key  = (unsigned long long*)carve((size_t)NTASK * D_N * 8);
  int* kept_cnt                 = (int*)carve((size_t)NTASK * 4);
  int* pick_flat                = (int*)carve((size_t)B_N * D_N * 4);

  hipLaunchKernelGGL(k1_softmax_decode, dim3(B_N * K1_NBLK), dim3(K1_APB), 0, stream,
                     cls, reg, anc, probs_t, boxes);
  hipLaunchKernelGGL(k2_topk, dim3(NTASK), dim3(256), 0, stream,
                     probs_t, topk_anchor, topk_score, topk_cnt);
  hipLaunchKernelGGL(k3_nms, dim3(NTASK), dim3(256), 0, stream,
                     boxes, topk_anchor, topk_score, topk_cnt, kept_key, kept_cnt);
  hipLaunchKernelGGL(k4_sel, dim3(B_N), dim3(256), 0, stream,
                     kept_key, kept_cnt, pick_flat);
  hipLaunchKernelGGL(k5_out, dim3(B_N * D_N / 4), dim3(256), 0, stream,
                     probs_t, boxes, topk_anchor, pick_flat, (float*)d_out);
}